// Round 15
// baseline (53.073 us; speedup 1.0000x reference)
//
#include <hip/hip_runtime.h>
#include <hip/hip_bf16.h>
#include <stdint.h>

#define N_W 96
#define NAG 192                      // total agents
#define NP1 97
#define W_ELEMS (N_W * NP1 * NP1)    // 903264 (divisible by 4)
#define R_ELEMS (NAG * NAG)          // 36864
#define WB ((W_ELEMS / 4 + 255) / 256)   // 883
#define RB ((R_ELEMS / 4 + 255) / 256)   // 36

// Decode one-hot tensors into packed index form + dictation times.
// packed word [a*64 + s] = pref[a][s] | (pref[a][s+64] << 16)
// ord[r] = dictating agent in round r; td[a] = round when agent a dictates.
__global__ __launch_bounds__(256) void decode_kernel(
    const float* __restrict__ W, const float* __restrict__ F,
    const float* __restrict__ R,
    short* __restrict__ ps, short* __restrict__ ord, short* __restrict__ td) {
    int b = blockIdx.x;
    if (b < 2 * WB) {
        const float* src = (b < WB) ? W : F;
        int abase = (b < WB) ? 0 : N_W;
        int i4 = (b - ((b < WB) ? 0 : WB)) * 256 + threadIdx.x;
        if (i4 < W_ELEMS / 4) {
            float4 v = ((const float4*)src)[i4];
            int base = i4 * 4;
            #pragma unroll
            for (int u = 0; u < 4; ++u) {
                float x = (u == 0) ? v.x : (u == 1) ? v.y : (u == 2) ? v.z : v.w;
                if (x > 0.5f) {
                    int idx = base + u;
                    int a = idx / (NP1 * NP1);
                    int rem = idx - a * (NP1 * NP1);
                    int j = rem / NP1;          // option (or 96=unmatch)
                    int k = rem - j * NP1;      // rank
                    int slot = (k < 64) ? (2 * k) : (2 * (k - 64) + 1);
                    ps[(abase + a) * 128 + slot] = (short)j;
                }
            }
        }
    } else {
        int i4 = (b - 2 * WB) * 256 + threadIdx.x;
        if (i4 < R_ELEMS / 4) {
            float4 v = ((const float4*)R)[i4];
            int base = i4 * 4;
            #pragma unroll
            for (int u = 0; u < 4; ++u) {
                float x = (u == 0) ? v.x : (u == 1) ? v.y : (u == 2) ? v.z : v.w;
                if (x > 0.5f) {
                    int idx = base + u;
                    int a = idx / NAG;
                    int r = idx - a * NAG;
                    ord[r] = (short)a;
                    td[a] = (short)r;
                }
            }
        }
    }
}

// Single-block sequential serial dictatorship.
// Group-of-4 interleaved LDS tiles: one ds_read_b128 per 4 rounds, issued a
// full group ahead -> no per-round LDS latency on the serial chain.
// Baked static removals (sentinel 97), chosen-only SGPR masks, branchy body.
__global__ __launch_bounds__(256, 1) void sd_kernel(
    const uint32_t* __restrict__ pk_g, const short* __restrict__ ord_g,
    const short* __restrict__ td_g, float* __restrict__ out) {
    __shared__ __align__(16) uint4 s_pk4[48 * 64 + 64];  // +64: prefetch overrun pad
    __shared__ uint32_t s_match[NAG];
    __shared__ unsigned short s_og[NAG];
    __shared__ unsigned short s_td[NAG];

    const int t = threadIdx.x;
    if (t < NAG) {
        s_og[t] = ((const unsigned short*)ord_g)[t];
        s_td[t] = ((const unsigned short*)td_g)[t];
    }
    __syncthreads();

    // staging: s_pk4[g*64 + lane] = {baked P[4g+i][lane]}_{i=0..3}
    // bake: pref j -> 97 (always-unavailable) if its owner dictates before r.
    for (int idx = t; idx < 48 * 64; idx += 256) {
        int g = idx >> 6, ln = idx & 63;
        uint32_t w[4];
        #pragma unroll
        for (int i = 0; i < 4; ++i) {
            int r = 4 * g + i;
            int a = (int)s_og[r];
            uint32_t x = pk_g[(a << 6) + ln];        // coalesced per (g,i)
            int opp = (a < 96) ? 96 : 0;
            uint32_t j1 = x & 0xFFFFu, j2 = x >> 16;
            if (j1 < 96u && (int)s_td[opp + j1] < r) j1 = 97u;
            if (j2 < 96u && (int)s_td[opp + j2] < r) j2 = 97u;
            w[i] = j1 | (j2 << 16);
        }
        s_pk4[idx] = make_uint4(w[0], w[1], w[2], w[3]);
    }
    __syncthreads();

    if (t < 64) {
        uint32_t ov0 = s_og[t], ov1 = s_og[64 + t], ov2 = s_og[128 + t];
        // chosen masks only (bit33 = sentinel-97, permanently unavailable)
        uint64_t chW = 0, chWh = (1ull << 33), chF = 0, chFh = (1ull << 33);
        uint32_t c0 = 0xFFFFFFFFu, c1 = 0xFFFFFFFFu, c2 = 0xFFFFFFFFu;
        uint4 Q = s_pk4[t];                          // group 0 prefs (4 rounds)

        auto ROUND = [&](uint32_t P, uint32_t ordv, int rr, uint32_t& cv) {
            int a = __builtin_amdgcn_readlane((int)ordv, rr);
            uint32_t j1 = P & 0xFFFFu;
            if (a < 96) {                            // worker dictates
                uint64_t own = (a < 64) ? chW : chWh;
                if (((own >> (a & 63)) & 1ull) == 0ull) {    // alive
                    uint32_t t0 = (uint32_t)(chF >> (j1 & 63u));
                    uint32_t t1 = (uint32_t)(chFh >> (j1 & 63u));
                    uint32_t bit = (j1 < 64u) ? t0 : t1;
                    unsigned long long m1 = __ballot((bit & 1u) == 0u);
                    uint32_t js;
                    if (m1 != 0ull) {
                        int k = __ffsll(m1) - 1;
                        js = ((uint32_t)__builtin_amdgcn_readlane((int)P, k)) & 0xFFFFu;
                    } else {                          // cold: rank>=64
                        uint32_t j2 = P >> 16;
                        uint32_t u0 = (uint32_t)(chF >> (j2 & 63u));
                        uint32_t u1 = (uint32_t)(chFh >> (j2 & 63u));
                        uint32_t b2 = (j2 < 64u) ? u0 : u1;
                        unsigned long long m2 = __ballot((b2 & 1u) == 0u) & 0x1FFFFFFFFull;
                        int k = __ffsll(m2) - 1;
                        js = ((uint32_t)__builtin_amdgcn_readlane((int)P, k)) >> 16;
                    }
                    if (js < 96u) {
                        if (js < 64u) chF |= 1ull << js; else chFh |= 1ull << (js & 63u);
                    }
                    uint32_t cell = (uint32_t)(a * NP1) + js;
                    cv = (t == (uint32_t)rr) ? cell : cv;    // lane-capture
                }
            } else {                                  // firm dictates
                int aa = a - 96;
                uint64_t own = (aa < 64) ? chF : chFh;
                if (((own >> (aa & 63)) & 1ull) == 0ull) {
                    uint32_t t0 = (uint32_t)(chW >> (j1 & 63u));
                    uint32_t t1 = (uint32_t)(chWh >> (j1 & 63u));
                    uint32_t bit = (j1 < 64u) ? t0 : t1;
                    unsigned long long m1 = __ballot((bit & 1u) == 0u);
                    uint32_t js;
                    if (m1 != 0ull) {
                        int k = __ffsll(m1) - 1;
                        js = ((uint32_t)__builtin_amdgcn_readlane((int)P, k)) & 0xFFFFu;
                    } else {
                        uint32_t j2 = P >> 16;
                        uint32_t u0 = (uint32_t)(chW >> (j2 & 63u));
                        uint32_t u1 = (uint32_t)(chWh >> (j2 & 63u));
                        uint32_t b2 = (j2 < 64u) ? u0 : u1;
                        unsigned long long m2 = __ballot((b2 & 1u) == 0u) & 0x1FFFFFFFFull;
                        int k = __ffsll(m2) - 1;
                        js = ((uint32_t)__builtin_amdgcn_readlane((int)P, k)) >> 16;
                    }
                    if (js < 96u) {
                        if (js < 64u) chW |= 1ull << js; else chWh |= 1ull << (js & 63u);
                    }
                    uint32_t cell = js * (uint32_t)NP1 + (uint32_t)aa;
                    cv = (t == (uint32_t)rr) ? cell : cv;
                }
            }
        };

        auto SEG = [&](uint32_t ordv, uint32_t& cv, int gbase) {
            #pragma clang loop unroll(disable)
            for (int g2 = 0; g2 < 16; ++g2) {
                int g = gbase + g2;
                uint4 Qn = s_pk4[((g + 1) << 6) + t];   // prefetch next group (4 rounds ahead)
                int rb = g2 << 2;
                ROUND(Q.x, ordv, rb + 0, cv);
                ROUND(Q.y, ordv, rb + 1, cv);
                ROUND(Q.z, ordv, rb + 2, cv);
                ROUND(Q.w, ordv, rb + 3, cv);
                Q = Qn;
            }
        };
        SEG(ov0, c0, 0);
        SEG(ov1, c1, 16);
        SEG(ov2, c2, 32);
        s_match[t] = c0; s_match[64 + t] = c1; s_match[128 + t] = c2;
    } else {
        // waves 1-3: zero-fill output concurrently with wave 0's loop
        for (int i = t - 64; i < 2352; i += 192)
            ((float4*)out)[i] = make_float4(0.f, 0.f, 0.f, 0.f);
        if (t == 64) out[9408] = 0.f;
    }
    __syncthreads();
    if (t < NAG) {
        uint32_t c = s_match[t];
        if (c != 0xFFFFFFFFu) out[c] = 1.0f;
    }
}

extern "C" void kernel_launch(void* const* d_in, const int* in_sizes, int n_in,
                              void* d_out, int out_size, void* d_ws, size_t ws_size,
                              hipStream_t stream) {
    const float* W = (const float*)d_in[0];
    const float* F = (const float*)d_in[1];
    const float* R = (const float*)d_in[2];
    float* out = (float*)d_out;

    uint32_t* packed = (uint32_t*)d_ws;                      // NAG*64 u32 = 48 KiB
    short* ord = (short*)((char*)d_ws + NAG * 64 * 4);       // 192 shorts
    short* td  = (short*)((char*)d_ws + NAG * 64 * 4 + NAG * 2);  // 192 shorts

    decode_kernel<<<2 * WB + RB, 256, 0, stream>>>(W, F, R, (short*)packed, ord, td);
    sd_kernel<<<1, 256, 0, stream>>>(packed, ord, td, out);
}